// Round 7
// baseline (79.657 us; speedup 1.0000x reference)
//
#include <hip/hip_runtime.h>
#include <math.h>

// Problem constants (B,J,H,W fixed by the reference setup).
#define BB 256
#define JJ 17
#define HWN 4096            // H*W
#define WW 64
#define JP (JJ * HWN)       // 69632  (j,p) pairs per tensor
#define ROWS (BB * JJ)      // 4352   (b,j) rows per tensor

#define NBC 8               // batch chunks of 32 (partial-buffer layout, verified)

typedef float f32x4 __attribute__((ext_vector_type(4)));

// -------- pass 1a (row-streaming): block = (tensor, j, b-chunk of 32, p-quarter).
// 8 waves/block; wave w streams 4 rows (same j, b = bc*32+w*4+{0..3}), each a
// CONTIGUOUS 4KB quarter-row of 4 pinned dwordx4 loads (pass2-shaped access,
// vs the 272KB-stride column walk that plateaued at ~2.9 TB/s in R1-R6).
// Per-lane: m[4][4] f32 max + s[4][4] f64 unshifted exp-sums (static indexed).
// 8-wave combine via 48KB LDS in 2 rounds -> same Pm/Ps partial layout as the
// absmax=0-verified pass1b. b-summation order stays ascending; f64 grouping
// change is ~1e-14 relative (slack is ~5e-7).
__global__ __launch_bounds__(512) void pckh_pass1a(
    const float* __restrict__ outp, const float* __restrict__ tgtp,
    float* __restrict__ Pm, double* __restrict__ Ps) {
  int blk = blockIdx.x;               // 0 .. 2*17*8*4-1 (= 4351)
  int t = blk / 544;                  // 17*8*4
  int rem = blk - t * 544;
  int j = rem >> 5;                   // 0..16
  int rem2 = rem & 31;
  int bc = rem2 >> 2;                 // 0..7
  int pq = rem2 & 3;                  // 0..3 (p-quarter of 1024)
  int tid = threadIdx.x;
  int w = tid >> 6, lane = tid & 63;
  const float* base = (t ? tgtp : outp);
  size_t poff = (size_t)j * HWN + (size_t)pq * 1024 + (size_t)lane * 4;
  int b0 = bc * 32 + w * 4;

  float m[4][4];
  double s[4][4];
#pragma unroll
  for (int o = 0; o < 4; ++o)
#pragma unroll
    for (int c = 0; c < 4; ++c) { m[o][c] = -INFINITY; s[o][c] = 0.0; }

#pragma unroll
  for (int rp = 0; rp < 2; ++rp) {
    const float* r0 = base + (size_t)((b0 + 2 * rp) * JJ) * HWN + poff;
    const float* r1 = base + (size_t)((b0 + 2 * rp + 1) * JJ) * HWN + poff;
    f32x4 a0 = *(const f32x4*)(r0 + 0 * 256);
    f32x4 a1 = *(const f32x4*)(r0 + 1 * 256);
    f32x4 a2 = *(const f32x4*)(r0 + 2 * 256);
    f32x4 a3 = *(const f32x4*)(r0 + 3 * 256);
    f32x4 c0 = *(const f32x4*)(r1 + 0 * 256);
    f32x4 c1 = *(const f32x4*)(r1 + 1 * 256);
    f32x4 c2 = *(const f32x4*)(r1 + 2 * 256);
    f32x4 c3 = *(const f32x4*)(r1 + 3 * 256);
    asm volatile("" : "+v"(a0), "+v"(a1), "+v"(a2), "+v"(a3),
                      "+v"(c0), "+v"(c1), "+v"(c2), "+v"(c3));
    f32x4 av[4] = {a0, a1, a2, a3};
    f32x4 cv[4] = {c0, c1, c2, c3};
#pragma unroll
    for (int o = 0; o < 4; ++o) {
#pragma unroll
      for (int c = 0; c < 4; ++c) {
        float x = av[o][c];               // row b0+2rp   (even b first:
        m[o][c] = fmaxf(m[o][c], x);      //  ascending-b sum order kept)
        s[o][c] += (double)expf(x);
        float y = cv[o][c];               // row b0+2rp+1
        m[o][c] = fmaxf(m[o][c], y);
        s[o][c] += (double)expf(y);
      }
    }
  }

  // 8-wave combine, 2 rounds of 512 p (48KB LDS).
  __shared__ float LM[8][512];
  __shared__ double LSUM[8][512];
  size_t gbase = ((size_t)(t * NBC + bc)) * JP + (size_t)j * HWN + (size_t)pq * 1024;
#pragma unroll
  for (int r = 0; r < 2; ++r) {
#pragma unroll
    for (int o2 = 0; o2 < 2; ++o2) {
      int o = 2 * r + o2;
#pragma unroll
      for (int c = 0; c < 4; ++c) {
        LM[w][o2 * 256 + lane * 4 + c] = m[o][c];
        LSUM[w][o2 * 256 + lane * 4 + c] = s[o][c];
      }
    }
    __syncthreads();
    {
      float mm = LM[0][tid];
      double ss = LSUM[0][tid];           // w ascending = b ascending
#pragma unroll
      for (int ww = 1; ww < 8; ++ww) {
        mm = fmaxf(mm, LM[ww][tid]);
        ss += LSUM[ww][tid];
      }
      Pm[gbase + r * 512 + tid] = mm;
      Ps[gbase + r * 512 + tid] = ss;
    }
    __syncthreads();
  }
}

// -------- pass 1b: combine the 8 b-chunk partials -> M, S.
// S = (sum_b exp(r)) * exp(-m) in double, rounded once to f32 — identical
// values to the absmax=0-verified formulation.
__global__ __launch_bounds__(256) void pckh_pass1b(
    const float* __restrict__ Pm, const double* __restrict__ Ps,
    float* __restrict__ M, float* __restrict__ S) {
  int gid = blockIdx.x * 256 + threadIdx.x;   // 0 .. 2*JP-1
  int t = gid / JP;
  int p = gid - t * JP;
  float m = -INFINITY;
  double s = 0.0;
#pragma unroll
  for (int bc = 0; bc < NBC; ++bc) {
    size_t idx = ((size_t)(t * NBC + bc)) * JP + p;
    m = fmaxf(m, Pm[idx]);
    s += Ps[idx];
  }
  M[gid] = m;
  S[gid] = (float)(s * exp(-(double)m));
}

// -------- fallback pass 1 (round-2 version) if d_ws can't hold partials.
#define PBLK 128
#define BGRP 8
__global__ __launch_bounds__(512) void pckh_pass1_fb(
    const float* __restrict__ outp, const float* __restrict__ tgtp,
    float* __restrict__ M, float* __restrict__ S) {
  int blk = blockIdx.x;
  int t = blk / (JP / PBLK);
  int pb = blk - t * (JP / PBLK);
  const float* src = (t ? tgtp : outp) + (size_t)pb * PBLK;
  int tid = threadIdx.x;
  int lane = tid & 63;
  int bg = tid >> 6;
  float m0 = -INFINITY, m1 = -INFINITY;
  double s0 = 0.0, s1 = 0.0;
#pragma unroll 8
  for (int i = 0; i < BB / BGRP; ++i) {
    int b = bg * (BB / BGRP) + i;
    float2 v = *(const float2*)(src + (size_t)b * JP + lane * 2);
    m0 = fmaxf(m0, v.x); m1 = fmaxf(m1, v.y);
    s0 += (double)expf(v.x); s1 += (double)expf(v.y);
  }
  __shared__ float sm[BGRP][PBLK];
  __shared__ double ss[BGRP][PBLK];
  sm[bg][lane * 2] = m0; sm[bg][lane * 2 + 1] = m1;
  ss[bg][lane * 2] = s0; ss[bg][lane * 2 + 1] = s1;
  __syncthreads();
  if (tid < PBLK) {
    float m = sm[0][tid];
    double s = ss[0][tid];
#pragma unroll
    for (int g = 1; g < BGRP; ++g) { m = fmaxf(m, sm[g][tid]); s += ss[g][tid]; }
    int gid = t * JP + pb * PBLK + tid;
    M[gid] = m;
    S[gid] = (float)(s * exp(-(double)m));
  }
}

// -------- pass 2: per (tensor, b, j) row, argmax_p of expf(r-m)/s with
// first-occurrence tie-break (matches jnp.argmax). float4 loads.
__global__ __launch_bounds__(256) void pckh_pass2(
    const float* __restrict__ outp, const float* __restrict__ tgtp,
    const float* __restrict__ M, const float* __restrict__ S,
    int* __restrict__ IDX) {
  int blk = blockIdx.x;          // 0 .. 2*ROWS-1
  int t = blk / ROWS;
  int row = blk - t * ROWS;      // b*JJ + j
  int j = row % JJ;
  const float4* src4 = (const float4*)((t ? tgtp : outp) + (size_t)row * HWN);
  const float4* M4 = (const float4*)(M + (size_t)t * JP + (size_t)j * HWN);
  const float4* S4 = (const float4*)(S + (size_t)t * JP + (size_t)j * HWN);

  int tid = threadIdx.x;
  float bv = -1.0f;  // all sm values are > 0
  int bi = 0;
#pragma unroll
  for (int g = 0; g < 4; ++g) {
    int p4 = g * 256 + tid;      // ascending p within thread
    float4 v = src4[p4];
    float4 m4 = M4[p4];
    float4 s4 = S4[p4];
    int p = p4 * 4;
    float e;
    e = expf(v.x - m4.x) / s4.x; if (e > bv) { bv = e; bi = p; }
    e = expf(v.y - m4.y) / s4.y; if (e > bv) { bv = e; bi = p + 1; }
    e = expf(v.z - m4.z) / s4.z; if (e > bv) { bv = e; bi = p + 2; }
    e = expf(v.w - m4.w) / s4.w; if (e > bv) { bv = e; bi = p + 3; }
  }
  __shared__ float sv[256];
  __shared__ int si[256];
  sv[tid] = bv;
  si[tid] = bi;
  __syncthreads();
  for (int off = 128; off > 0; off >>= 1) {
    if (tid < off) {
      float v2 = sv[tid + off];
      int i2 = si[tid + off];
      if (v2 > sv[tid] || (v2 == sv[tid] && i2 < si[tid])) {
        sv[tid] = v2;
        si[tid] = i2;
      }
    }
    __syncthreads();
  }
  if (tid == 0) IDX[blk] = si[0];
}

// -------- pass 3: counts -> [avg, acc_j...]   (maxvals>0 mask is always true)
__global__ __launch_bounds__(256) void pckh_pass3(
    const int* __restrict__ IDX, float* __restrict__ outv) {
  __shared__ int num[JJ], below[JJ];
  __shared__ float accj[JJ];
  int tid = threadIdx.x;
  if (tid < JJ) { num[tid] = 0; below[tid] = 0; }
  __syncthreads();
  for (int row = tid; row < ROWS; row += 256) {
    int j = row % JJ;
    int io = IDX[row];
    int it = IDX[ROWS + row];
    float pox = (float)(io & (WW - 1));
    float poy = (float)(io >> 6);
    float ptx = (float)(it & (WW - 1));
    float pty = (float)(it >> 6);
    if (ptx > 1.0f && pty > 1.0f) {
      atomicAdd(&num[j], 1);
      const float nrm = 6.4f;  // float32(64)/float32(10), same as jnp
      float dx = (pox - ptx) / nrm;
      float dy = (poy - pty) / nrm;
      float d = sqrtf(dx * dx + dy * dy);
      if (d < 0.5f) atomicAdd(&below[j], 1);
    }
  }
  __syncthreads();
  if (tid < JJ) {
    accj[tid] = num[tid] > 0 ? (float)below[tid] / (float)num[tid] : -1.0f;
    outv[1 + tid] = accj[tid];
  }
  __syncthreads();
  if (tid == 0) {
    float sum = 0.0f;
    int cnt = 0;
    for (int j = 0; j < JJ; ++j)
      if (accj[j] >= 0.0f) { sum += accj[j]; cnt++; }
    outv[0] = cnt > 0 ? sum / (float)cnt : 0.0f;
  }
}

extern "C" void kernel_launch(void* const* d_in, const int* in_sizes, int n_in,
                              void* d_out, int out_size, void* d_ws, size_t ws_size,
                              hipStream_t stream) {
  const float* outp = (const float*)d_in[0];
  const float* tgtp = (const float*)d_in[1];
  float* outv = (float*)d_out;

  // workspace layout: M[2*JP] f32 | S[2*JP] f32 | IDX[2*ROWS] i32 |
  //                   Pm[2*NBC*JP] f32 | Ps[2*NBC*JP] f64
  float* M = (float*)d_ws;
  float* S = M + 2 * JP;
  int* IDX = (int*)(S + 2 * JP);
  size_t base = (size_t)2 * JP * 4 * 2 + (size_t)2 * ROWS * 4;  // bytes used so far
  base = (base + 255) & ~(size_t)255;                            // align 256
  size_t pm_bytes = (size_t)2 * NBC * JP * sizeof(float);
  size_t ps_bytes = (size_t)2 * NBC * JP * sizeof(double);
  float* Pm = (float*)((char*)d_ws + base);
  double* Ps = (double*)((char*)d_ws + base + pm_bytes);
  size_t need = base + pm_bytes + ps_bytes;

  if (ws_size >= need) {
    pckh_pass1a<<<2 * 17 * 8 * 4, 512, 0, stream>>>(outp, tgtp, Pm, Ps);
    pckh_pass1b<<<(2 * JP) / 256, 256, 0, stream>>>(Pm, Ps, M, S);
  } else {
    pckh_pass1_fb<<<(2 * JP) / PBLK, 512, 0, stream>>>(outp, tgtp, M, S);
  }
  pckh_pass2<<<2 * ROWS, 256, 0, stream>>>(outp, tgtp, M, S, IDX);
  pckh_pass3<<<1, 256, 0, stream>>>(IDX, outv);
}